// Round 12
// baseline (70.468 us; speedup 1.0000x reference)
//
#include <hip/hip_runtime.h>

typedef __attribute__((ext_vector_type(8))) __bf16 bf16x8;
typedef __attribute__((ext_vector_type(4))) float f32x4;

#define T_HI 0.97467943f   // sqrt(0.95)
#define T_LO 0.70710678f   // sqrt(0.5)

__device__ __forceinline__ bf16x8 cvt8(float4 a, float4 b) {
    return bf16x8{(__bf16)a.x, (__bf16)a.y, (__bf16)a.z, (__bf16)a.w,
                  (__bf16)b.x, (__bf16)b.y, (__bf16)b.z, (__bf16)b.w};
}

// Barrier-free streaming design: one block = 16-row strip x all cols of one batch.
// 256 threads = 4 waves, each wave free-runs over its 32-panel-row slice per step.
// No panel LDS, no in-loop barrier: A-fragments load global->reg (8 contiguous
// fp32 per lane), convert to bf16 in-reg. 1-deep prefetch puts next loads BEFORE
// this iter's stores in issue order, so vmcnt waits never drain the store queue.
// Grid: (N/16)*8 = 1024 blocks = exactly 4 blocks/CU; batch = id & 7 (XCD L2 reuse).
__global__ __launch_bounds__(256) void lap_wave_kernel(
    const float* __restrict__ X, float* __restrict__ out, int N)
{
    const int flat   = blockIdx.x;
    const int b      = flat & 7;
    const int strip0 = (flat >> 3) * 16;
    const int tid  = threadIdx.x;     // 0..255
    const int lane = tid & 63;
    const int w    = tid >> 6;        // wave 0..3
    const int t    = lane & 15;
    const int g    = lane >> 4;

    __shared__ float deg_part[4][16];

    const float* Xb   = X   + (size_t)b * N * 64;
    float*       outb = out + (size_t)b * N * N;

    const int orow = strip0 + t;      // this lane's output row (strip side)

    // ---- strip B-fragments: rows strip0..+16, loaded once, global->reg ----
    bf16x8 bfrag[2];
#pragma unroll
    for (int ks = 0; ks < 2; ++ks) {
        const float* p = Xb + (size_t)(strip0 + t) * 64 + ks * 32 + g * 8;
        float4 r0 = *reinterpret_cast<const float4*>(p);
        float4 r1 = *reinterpret_cast<const float4*>(p + 4);
        bfrag[ks] = cvt8(r0, r1);
    }

    // raw A buffers: 4 fragments x 2 float4 (fragment f = ks*2+fi)
    float4 rawA[8], rawB[8];

    // per-step A-slice base row: 128*ct + 32*w + 16*fi + t, k = ks*32 + g*8
#define ISSUE(ct_, buf_)                                                        \
    {                                                                           \
        _Pragma("unroll")                                                       \
        for (int f = 0; f < 4; ++f) {                                           \
            const int ks_ = f >> 1, fi_ = f & 1;                                \
            const float* p_ = Xb + (size_t)(128 * (ct_) + 32 * w + 16 * fi_ + t) * 64 \
                               + ks_ * 32 + g * 8;                              \
            buf_[2 * f]     = *reinterpret_cast<const float4*>(p_);             \
            buf_[2 * f + 1] = *reinterpret_cast<const float4*>(p_ + 4);         \
        }                                                                       \
    }

#define STEP(ct_, buf_)                                                         \
    {                                                                           \
        f32x4 acc0 = {}, acc1 = {};                                             \
        bf16x8 a_;                                                              \
        a_ = cvt8(buf_[0], buf_[1]);                                            \
        acc0 = __builtin_amdgcn_mfma_f32_16x16x32_bf16(a_, bfrag[0], acc0, 0, 0, 0); \
        a_ = cvt8(buf_[2], buf_[3]);                                            \
        acc1 = __builtin_amdgcn_mfma_f32_16x16x32_bf16(a_, bfrag[0], acc1, 0, 0, 0); \
        a_ = cvt8(buf_[4], buf_[5]);                                            \
        acc0 = __builtin_amdgcn_mfma_f32_16x16x32_bf16(a_, bfrag[1], acc0, 0, 0, 0); \
        a_ = cvt8(buf_[6], buf_[7]);                                            \
        acc1 = __builtin_amdgcn_mfma_f32_16x16x32_bf16(a_, bfrag[1], acc1, 0, 0, 0); \
        _Pragma("unroll")                                                       \
        for (int fi_ = 0; fi_ < 2; ++fi_) {                                     \
            const f32x4 A_ = fi_ ? acc1 : acc0;                                 \
            const int ocol0_ = 128 * (ct_) + 32 * w + 16 * fi_ + 4 * g;         \
            f32x4 st_;                                                          \
            _Pragma("unroll")                                                   \
            for (int r_ = 0; r_ < 4; ++r_) {                                    \
                const float d_ = A_[r_];                                        \
                float wt_ = (fabsf(d_) >= T_HI) ? 1.0f                          \
                          : ((fabsf(d_) >= T_LO) ? 0.5f : 0.0f);                \
                if (ocol0_ + r_ == orow) wt_ = 0.0f;                            \
                rs += wt_;                                                      \
                st_[r_] = -wt_;                                                 \
            }                                                                   \
            *reinterpret_cast<f32x4*>(&outb[(size_t)orow * N + ocol0_]) = st_;  \
        }                                                                       \
    }

    float rs = 0.f;
    ISSUE(0, rawA);                      // prologue

    for (int ct = 0; ct < 16; ct += 2) {
        ISSUE(ct + 1, rawB);             // loads for ct+1 issued BEFORE ct's stores
        STEP(ct, rawA);
        if (ct + 2 < 16) ISSUE(ct + 2, rawA);
        STEP(ct + 1, rawB);
    }
#undef ISSUE
#undef STEP

    // ---- degree: reduce over g via shfl, across 4 waves via LDS ----
    rs += __shfl_xor(rs, 16, 64);
    rs += __shfl_xor(rs, 32, 64);
    if (g == 0) deg_part[w][t] = rs;
    __syncthreads();                     // drains vmcnt too: tile stores land first
    if (tid < 16) {
        const float d = deg_part[0][tid] + deg_part[1][tid]
                      + deg_part[2][tid] + deg_part[3][tid];
        const int rr = strip0 + tid;
        outb[(size_t)rr * N + rr] = d;   // diagonal = degree
    }
}

extern "C" void kernel_launch(void* const* d_in, const int* in_sizes, int n_in,
                              void* d_out, int out_size, void* d_ws, size_t ws_size,
                              hipStream_t stream) {
    const float* X = (const float*)d_in[0];
    float* out = (float*)d_out;

    const int B = 8;
    const int D = 64;
    const int N = in_sizes[0] / (B * D);   // 2048

    dim3 grid((N / 16) * B);               // 1024 blocks = 4 per CU
    lap_wave_kernel<<<grid, dim3(256), 0, stream>>>(X, out, N);
}

// Round 14
// 35.667 us; speedup vs baseline: 1.9757x; 1.9757x over previous
//
#include <hip/hip_runtime.h>

typedef __attribute__((ext_vector_type(8))) __bf16 bf16x8;
typedef __attribute__((ext_vector_type(4))) __bf16 bf16x4;
typedef __attribute__((ext_vector_type(4))) float f32x4;

#define LDST 68     // panel/strip LDS row stride in bf16 (136 B)
#define SROW 1032   // u8 stage row stride in bytes (1024 + 8 pad)

#define T_HI 0.97467943f   // sqrt(0.95)
#define T_LO 0.70710678f   // sqrt(0.5)

// Barrier draining only LDS ops (lgkmcnt) — global stores stay in flight.
__device__ __forceinline__ void lds_barrier() {
    asm volatile("s_waitcnt lgkmcnt(0)" ::: "memory");
    __builtin_amdgcn_s_barrier();
    __builtin_amdgcn_sched_barrier(0);
}
// Full drain — once, before the diagonal overwrite.
__device__ __forceinline__ void full_barrier() {
    asm volatile("s_waitcnt vmcnt(0) lgkmcnt(0)" ::: "memory");
    __builtin_amdgcn_s_barrier();
    __builtin_amdgcn_sched_barrier(0);
}

// Block = 32-row strip x all 2048 cols of one batch. 512 threads = 8 waves.
// Compute phase encodes w as u8 {0,1,2} into an LDS stage (32 x 1024 per half);
// flush phase writes each row SEQUENTIALLY: wave w owns rows 4w..4w+3, emitting
// 16 KB of strictly ascending addresses (4 rows x 4 KB). Global stores happen
// ONLY in flush phases -> long sequential HBM write streams, fill-kernel-like.
__global__ __launch_bounds__(512) void lap_stage_kernel(
    const float* __restrict__ X, float* __restrict__ out, int N)
{
    const int flat   = blockIdx.x;
    const int b      = flat & 7;              // batch -> XCD (L2 panel reuse)
    const int strip0 = (flat >> 3) * 32;
    const int tid  = threadIdx.x;             // 0..511
    const int lane = tid & 63;
    const int w    = tid >> 6;                // wave 0..7
    const int t    = lane & 15;
    const int g    = lane >> 4;

    __shared__ __align__(16) unsigned short As[128 * LDST];   // panel tile (single buf, 17.4 KB)
    __shared__ __align__(16) unsigned short Bs[32 * LDST];    // strip (4.4 KB)
    __shared__ __align__(4)  unsigned char  St[32 * SROW];    // u8 weight stage (33 KB)
    __shared__ float deg_part[8][32];

    const float* Xb   = X   + (size_t)b * N * 64;
    float*       outb = out + (size_t)b * N * N;

    // ---- prologue: stage strip rows (32 x 64 fp32 -> bf16; one float4/thread) ----
    {
        const float4* src = reinterpret_cast<const float4*>(Xb + (size_t)strip0 * 64);
        int r = tid >> 4, q = tid & 15;
        float4 v = src[tid];
        bf16x4 h = {(__bf16)v.x, (__bf16)v.y, (__bf16)v.z, (__bf16)v.w};
        *reinterpret_cast<bf16x4*>(&Bs[r * LDST + q * 4]) = h;
    }
    // prologue: load panel tile 0 into regs (128 rows x 16 float4 / 512 thr = 4 each)
    float4 pre[4];
    {
        const float4* src = reinterpret_cast<const float4*>(Xb);
#pragma unroll
        for (int it = 0; it < 4; ++it) pre[it] = src[tid + it * 512];
    }
    lds_barrier();

    // strip fragments: loop-invariant
    bf16x8 bfrag[2][2];   // [ks][fj]
#pragma unroll
    for (int ks = 0; ks < 2; ++ks)
#pragma unroll
        for (int fj = 0; fj < 2; ++fj)
            bfrag[ks][fj] = *reinterpret_cast<const bf16x8*>(
                &Bs[(16 * fj + t) * LDST + ks * 32 + g * 8]);

    float rs[2] = {0.f, 0.f};

    for (int half = 0; half < 2; ++half) {
#pragma unroll 1
        for (int ctl = 0; ctl < 8; ++ctl) {
            const int ct = half * 8 + ctl;

            // write panel tile from regs into As
#pragma unroll
            for (int it = 0; it < 4; ++it) {
                int idx = tid + it * 512;
                int r = idx >> 4, q = idx & 15;
                float4 v = pre[it];
                bf16x4 h = {(__bf16)v.x, (__bf16)v.y, (__bf16)v.z, (__bf16)v.w};
                *reinterpret_cast<bf16x4*>(&As[r * LDST + q * 4]) = h;
            }
            lds_barrier();

            // prefetch next panel tile (covers the half boundary too)
            if (ct + 1 < 16) {
                const float4* src = reinterpret_cast<const float4*>(
                    Xb + (size_t)(ct + 1) * 128 * 64);
#pragma unroll
                for (int it = 0; it < 4; ++it) pre[it] = src[tid + it * 512];
            }

            // ---- MFMA: wave w -> panel rows [16w,16w+16) x strip 32 rows ----
            f32x4 acc[2] = {};   // [fj]
#pragma unroll
            for (int ks = 0; ks < 2; ++ks) {
                const int koff = ks * 32 + g * 8;
                bf16x8 a = *reinterpret_cast<const bf16x8*>(
                    &As[(16 * w + t) * LDST + koff]);
#pragma unroll
                for (int fj = 0; fj < 2; ++fj)
                    acc[fj] = __builtin_amdgcn_mfma_f32_16x16x32_bf16(
                        a, bfrag[ks][fj], acc[fj], 0, 0, 0);
            }

            // ---- encode weights u8 {0,1,2} into stage ----
            const int scol0 = 128 * ctl + 16 * w + 4 * g;       // col within half
            const int gcol0 = half * 1024 + scol0;              // global col
#pragma unroll
            for (int fj = 0; fj < 2; ++fj) {
                const int orow = strip0 + 16 * fj + t;
                unsigned int pack = 0;
#pragma unroll
                for (int r = 0; r < 4; ++r) {
                    const float d = acc[fj][r];
                    unsigned int code = (fabsf(d) >= T_HI) ? 2u
                                      : ((fabsf(d) >= T_LO) ? 1u : 0u);
                    if (gcol0 + r == orow) code = 0u;
                    rs[fj] += 0.5f * (float)code;
                    pack |= code << (8 * r);
                }
                *reinterpret_cast<unsigned int*>(
                    &St[(16 * fj + t) * SROW + scol0]) = pack;
            }
            lds_barrier();   // As consumed + stage writes visible
        }

        // ---- flush: sequential row-order stores; wave w -> rows 4w..4w+3 ----
#pragma unroll
        for (int rr = 0; rr < 4; ++rr) {
            const int row  = 4 * w + rr;
            const int grow = strip0 + row;
            const unsigned char* sp = &St[row * SROW];
            float* dst = &outb[(size_t)grow * N + half * 1024];
#pragma unroll
            for (int seg = 0; seg < 4; ++seg) {
                unsigned int u = *reinterpret_cast<const unsigned int*>(
                    &sp[seg * 256 + 4 * lane]);          // 4 segs x 256 B = one 1 KB row
                f32x4 v = { -0.5f * (float)( u        & 0xffu),
                            -0.5f * (float)((u >> 8)  & 0xffu),
                            -0.5f * (float)((u >> 16) & 0xffu),
                            -0.5f * (float)((u >> 24) & 0xffu) };
                *reinterpret_cast<f32x4*>(&dst[seg * 256 + 4 * lane]) = v;
            }
        }
        // next half's first stage-write is after the next lds_barrier -> safe
    }

    // ---- degree: reduce over g via shfl, across 8 waves via LDS ----
    rs[0] += __shfl_xor(rs[0], 16, 64); rs[0] += __shfl_xor(rs[0], 32, 64);
    rs[1] += __shfl_xor(rs[1], 16, 64); rs[1] += __shfl_xor(rs[1], 32, 64);
    if (g == 0) { deg_part[w][t] = rs[0]; deg_part[w][16 + t] = rs[1]; }
    full_barrier();   // all tile stores must land before the diagonal overwrite
    if (tid < 32) {
        float d = 0.f;
#pragma unroll
        for (int ww = 0; ww < 8; ++ww) d += deg_part[ww][tid];
        const int rr = strip0 + tid;
        outb[(size_t)rr * N + rr] = d;   // diagonal = degree
    }
}

extern "C" void kernel_launch(void* const* d_in, const int* in_sizes, int n_in,
                              void* d_out, int out_size, void* d_ws, size_t ws_size,
                              hipStream_t stream) {
    const float* X = (const float*)d_in[0];
    float* out = (float*)d_out;

    const int B = 8;
    const int D = 64;
    const int N = in_sizes[0] / (B * D);   // 2048

    dim3 grid((N / 32) * B);               // 512 blocks, batch = id & 7
    lap_stage_kernel<<<grid, dim3(512), 0, stream>>>(X, out, N);
}

// Round 15
// 29.707 us; speedup vs baseline: 2.3721x; 1.2006x over previous
//
#include <hip/hip_runtime.h>

typedef __attribute__((ext_vector_type(8))) __bf16 bf16x8;
typedef __attribute__((ext_vector_type(4))) __bf16 bf16x4;
typedef __attribute__((ext_vector_type(4))) float f32x4;

#define LDST 68   // LDS row stride in bf16 (136 B): 2-bank row skew, b128 reads conflict-free

#define T_HI 0.97467943f   // sqrt(0.95)
#define T_LO 0.70710678f   // sqrt(0.5)

// Barrier draining only LDS ops (lgkmcnt) — global stores stay in flight.
__device__ __forceinline__ void lds_barrier() {
    asm volatile("s_waitcnt lgkmcnt(0)" ::: "memory");
    __builtin_amdgcn_s_barrier();
    __builtin_amdgcn_sched_barrier(0);
}
// Full drain — once, before the diagonal overwrite.
__device__ __forceinline__ void full_barrier() {
    asm volatile("s_waitcnt vmcnt(0) lgkmcnt(0)" ::: "memory");
    __builtin_amdgcn_s_barrier();
    __builtin_amdgcn_sched_barrier(0);
}

// Block = 64-row strip x all 2048 cols of one batch. 1024 threads = 16 waves;
// wave w owns panel rows [16w,16w+16) of each 256-wide column tile.
// Grid: 256 blocks (= 1/CU, 16 waves/CU) -> panel re-read volume halved vs
// 32-row strips (134 MB total), relieving L3/fabric read interference with the
// 134 MB store stream. batch = id & 7 (one batch per XCD for L2 panel locality).
__global__ __launch_bounds__(1024, 4) void lap_strip64_kernel(
    const float* __restrict__ X, float* __restrict__ out, int N)
{
    const int flat   = blockIdx.x;
    const int b      = flat & 7;
    const int strip0 = (flat >> 3) * 64;
    const int tid  = threadIdx.x;     // 0..1023
    const int lane = tid & 63;
    const int w    = tid >> 6;        // wave 0..15
    const int t    = lane & 15;
    const int g    = lane >> 4;

    __shared__ __align__(16) unsigned short As[2][256 * LDST];  // 256-row col-panel, double-buffered (68 KB)
    __shared__ __align__(16) unsigned short Bs[64 * LDST];      // strip (loop-invariant, 8.7 KB)
    __shared__ float deg_part[16][64];

    const float* Xb   = X   + (size_t)b * N * 64;
    float*       outb = out + (size_t)b * N * N;

    // ---- stage strip rows: 64 x 64 fp32 -> bf16 (1024 float4, one per thread) ----
    {
        const float4* src = reinterpret_cast<const float4*>(Xb + (size_t)strip0 * 64);
        int r = tid >> 4, q = tid & 15;
        float4 v = src[tid];
        bf16x4 h = {(__bf16)v.x, (__bf16)v.y, (__bf16)v.z, (__bf16)v.w};
        *reinterpret_cast<bf16x4*>(&Bs[r * LDST + q * 4]) = h;
    }

    // ---- stage col-panel 0 into As[0] (256 rows = 4096 float4 = 4 per thread) ----
    float4 pre[4];
    {
        const float4* src = reinterpret_cast<const float4*>(Xb);
#pragma unroll
        for (int it = 0; it < 4; ++it) pre[it] = src[tid + it * 1024];
#pragma unroll
        for (int it = 0; it < 4; ++it) {
            int idx = tid + it * 1024;
            int r = idx >> 4, q = idx & 15;
            float4 v = pre[it];
            bf16x4 h = {(__bf16)v.x, (__bf16)v.y, (__bf16)v.z, (__bf16)v.w};
            *reinterpret_cast<bf16x4*>(&As[0][r * LDST + q * 4]) = h;
        }
    }
    lds_barrier();

    // strip fragments: loop-invariant (4 fj covering 64 strip rows)
    bf16x8 bfrag[2][4];   // [ks][fj]
#pragma unroll
    for (int ks = 0; ks < 2; ++ks)
#pragma unroll
        for (int fj = 0; fj < 4; ++fj)
            bfrag[ks][fj] = *reinterpret_cast<const bf16x8*>(
                &Bs[(16 * fj + t) * LDST + ks * 32 + g * 8]);

    float rs[4] = {0.f, 0.f, 0.f, 0.f};
    int cur = 0;
    const int nct = N >> 8;            // 8 column tiles of 256
    const int diag_ct = strip0 >> 8;   // 64-row strip never straddles a 256 boundary

    for (int ct = 0; ct < nct; ++ct) {
        // prefetch next 256-row panel into regs (loads issued BEFORE this iter's stores)
        if (ct + 1 < nct) {
            const float4* src = reinterpret_cast<const float4*>(Xb + (size_t)(ct + 1) * 256 * 64);
#pragma unroll
            for (int it = 0; it < 4; ++it) pre[it] = src[tid + it * 1024];
        }

        // ---- compute: wave w -> panel rows [16w,16w+16) x strip 64 rows ----
        f32x4 acc[4] = {};   // [fj]
#pragma unroll
        for (int ks = 0; ks < 2; ++ks) {
            const int koff = ks * 32 + g * 8;
            bf16x8 a = *reinterpret_cast<const bf16x8*>(
                &As[cur][(16 * w + t) * LDST + koff]);
#pragma unroll
            for (int fj = 0; fj < 4; ++fj)
                acc[fj] = __builtin_amdgcn_mfma_f32_16x16x32_bf16(
                    a, bfrag[ks][fj], acc[fj], 0, 0, 0);
        }

        // ---- epilogue: |d| thresholds; transposed store -> contiguous f32x4 ----
        const bool has_diag = (ct == diag_ct);
        const int ocol0 = ct * 256 + 16 * w + 4 * g;      // output col base (panel side)
#pragma unroll
        for (int fj = 0; fj < 4; ++fj) {
            const int orow = strip0 + 16 * fj + t;        // output row (strip side)
            float wv[4];
#pragma unroll
            for (int r = 0; r < 4; ++r) {
                const float d = acc[fj][r];
                float wt = (fabsf(d) >= T_HI) ? 1.0f
                         : ((fabsf(d) >= T_LO) ? 0.5f : 0.0f);
                if (has_diag && (ocol0 + r == orow)) wt = 0.0f;
                rs[fj] += wt;
                wv[r] = -wt;
            }
            f32x4 st = {wv[0], wv[1], wv[2], wv[3]};
            *reinterpret_cast<f32x4*>(&outb[(size_t)orow * N + ocol0]) = st;
        }

        // ---- write next panel into the other buffer ----
        if (ct + 1 < nct) {
#pragma unroll
            for (int it = 0; it < 4; ++it) {
                int idx = tid + it * 1024;
                int r = idx >> 4, q = idx & 15;
                float4 v = pre[it];
                bf16x4 h = {(__bf16)v.x, (__bf16)v.y, (__bf16)v.z, (__bf16)v.w};
                *reinterpret_cast<bf16x4*>(&As[cur ^ 1][r * LDST + q * 4]) = h;
            }
        }
        lds_barrier();
        cur ^= 1;
    }

    // ---- degree: reduce over g via shfl, across 16 waves via LDS ----
#pragma unroll
    for (int fj = 0; fj < 4; ++fj) {
        rs[fj] += __shfl_xor(rs[fj], 16, 64);
        rs[fj] += __shfl_xor(rs[fj], 32, 64);
    }
    if (g == 0) {
#pragma unroll
        for (int fj = 0; fj < 4; ++fj) deg_part[w][16 * fj + t] = rs[fj];
    }
    full_barrier();   // all tile stores must land before the diagonal overwrite
    if (tid < 64) {
        float d = 0.f;
#pragma unroll
        for (int ww = 0; ww < 16; ++ww) d += deg_part[ww][tid];
        const int rr = strip0 + tid;
        outb[(size_t)rr * N + rr] = d;   // diagonal = degree
    }
}

extern "C" void kernel_launch(void* const* d_in, const int* in_sizes, int n_in,
                              void* d_out, int out_size, void* d_ws, size_t ws_size,
                              hipStream_t stream) {
    const float* X = (const float*)d_in[0];
    float* out = (float*)d_out;

    const int B = 8;
    const int D = 64;
    const int N = in_sizes[0] / (B * D);   // 2048

    dim3 grid((N / 64) * B);               // 256 blocks, batch = id & 7
    lap_strip64_kernel<<<grid, dim3(1024), 0, stream>>>(X, out, N);
}